// Round 8
// baseline (393.044 us; speedup 1.0000x reference)
//
#include <hip/hip_runtime.h>
#include <hip/hip_bf16.h>

typedef __hip_bfloat16 bf16;
typedef short v8s __attribute__((ext_vector_type(8)));   // 8 bf16 (4 VGPRs), MFMA A/B frag
typedef float v4f __attribute__((ext_vector_type(4)));   // MFMA C/D frag

constexpr int NN    = 50000;   // nodes
constexpr int NE    = 800000;  // raw edges
constexpr int NETOT = 850000;  // + self loops
constexpr int CIN   = 256;
constexpr int HC    = 256;     // H*C
constexpr int NH    = 4;
constexpr int NOUT  = 40;
constexpr int NPAD  = 48;      // W2T padded cols (3 x 16)
constexpr int SCB   = 196;     // scan blocks (196*256 >= NN)

// ---------------- workspace layout ----------------
constexpr size_t al256(size_t x){ return (x + 255) & ~(size_t)255; }
constexpr size_t WS_FLAGS = 0;                                   // 2 ints
constexpr size_t WS_EW1   = 256;                                 // NETOT float4
constexpr size_t WS_W1T   = al256(WS_EW1   + (size_t)NETOT*16);  // [n][k] 256x256 bf16
constexpr size_t WS_AS1N  = al256(WS_W1T   + (size_t)CIN*HC*2);
constexpr size_t WS_AD1N  = al256(WS_AS1N  + HC*2);
constexpr size_t WS_B1N   = al256(WS_AD1N  + HC*2);
constexpr size_t WS_W2T   = al256(WS_B1N   + HC*2);              // [n][k] 48x256 bf16 (zero-padded)
constexpr size_t WS_AS2N  = al256(WS_W2T   + (size_t)NPAD*HC*2);
constexpr size_t WS_AD2N  = al256(WS_AS2N  + NOUT*2);
constexpr size_t WS_B2N   = al256(WS_AD2N  + NOUT*2);
constexpr size_t WS_ES    = al256(WS_B2N   + NOUT*2);            // NE int32
constexpr size_t WS_ED    = al256(WS_ES    + (size_t)NE*4);
constexpr size_t WS_COUNTS= al256(WS_ED    + (size_t)NE*4);
constexpr size_t WS_CURSOR= al256(WS_COUNTS+ (size_t)NN*4);
constexpr size_t WS_ROWPTR= al256(WS_CURSOR+ (size_t)NN*4);
constexpr size_t WS_EIDX  = al256(WS_ROWPTR+ (size_t)(NN+1)*4);
constexpr size_t WS_DPOS  = al256(WS_EIDX  + (size_t)NETOT*4);   // NETOT int32 (dst per CSR slot)
constexpr size_t WS_H1    = al256(WS_DPOS  + (size_t)NETOT*4);   // NN*HC fp8 (1B)
constexpr size_t WS_ALS1  = al256(WS_H1    + (size_t)NN*HC);
constexpr size_t WS_ALD1  = al256(WS_ALS1  + (size_t)NN*NH*4);
constexpr size_t WS_Y1    = al256(WS_ALD1  + (size_t)NN*NH*4);   // NN*HC bf16
constexpr size_t WS_H2    = al256(WS_Y1    + (size_t)NN*HC*2);   // NN*NOUT bf16
constexpr size_t WS_ALS2  = al256(WS_H2    + (size_t)NN*NOUT*2);
constexpr size_t WS_ALD2  = al256(WS_ALS2  + (size_t)NN*4);
constexpr size_t WS_EW2   = al256(WS_ALD2  + (size_t)NN*4);      // NETOT float
constexpr size_t WS_BSUM  = al256(WS_EW2   + (size_t)NETOT*4);   // 256 int
constexpr size_t WS_BOFF  = al256(WS_BSUM  + 1024);              // 256 int

// ---------------- convert virtual index space (x handled in gemm1 now) ---------
constexpr int CV_W1  = 0;
constexpr int CV_AS1 = CV_W1  + CIN*HC;
constexpr int CV_AD1 = CV_AS1 + HC;
constexpr int CV_B1  = CV_AD1 + HC;
constexpr int CV_W2  = CV_B1  + HC;
constexpr int CV_AS2 = CV_W2  + HC*NOUT;
constexpr int CV_AD2 = CV_AS2 + NOUT;
constexpr int CV_B2  = CV_AD2 + NOUT;
constexpr int CV_ES  = CV_B2  + NOUT;
constexpr int CV_ED  = CV_ES  + NE;
constexpr int CV_END = CV_ED  + NE;

__device__ __forceinline__ float b2f(bf16 v) { return __bfloat162float(v); }
__device__ __forceinline__ bf16  f2b(float v){ return __float2bfloat16(v); }
__device__ __forceinline__ float bits2f(unsigned short u){ return __uint_as_float(((unsigned)u) << 16); }
__device__ __forceinline__ unsigned short f2bits(float v){
  bf16 t = __float2bfloat16(v);
  return *reinterpret_cast<unsigned short*>(&t);
}
__device__ __forceinline__ float lrelu(float x){ return x > 0.f ? x : 0.2f * x; }

__device__ __forceinline__ float wave_sum(float v){
  #pragma unroll
  for (int off = 32; off; off >>= 1) v += __shfl_xor(v, off, 64);
  return v;
}
__device__ __forceinline__ float wave_max(float v){
  #pragma unroll
  for (int off = 32; off; off >>= 1) v = fmaxf(v, __shfl_xor(v, off, 64));
  return v;
}

// ---------------- dtype detection (bf16 vs f32 floats; i32 vs i64 edges) --------
__global__ __launch_bounds__(64) void k_detect(const unsigned short* __restrict__ xu,
                                               const unsigned* __restrict__ eu,
                                               int* __restrict__ flags){
  int lane = threadIdx.x;
  int cnt = 0;
  for (int i = lane; i < 256; i += 64){
    int e = (xu[i] >> 7) & 0xFF;
    cnt += (e >= 0x60 && e <= 0x8F) ? 1 : 0;
  }
  #pragma unroll
  for (int off = 32; off; off >>= 1) cnt += __shfl_xor(cnt, off, 64);
  unsigned odd = eu[2 * lane + 1];
  #pragma unroll
  for (int off = 32; off; off >>= 1) odd |= __shfl_xor(odd, off, 64);
  if (lane == 0){
    flags[0] = (cnt < 218) ? 1 : 0;   // 1 = floats are f32
    flags[1] = (odd == 0)  ? 1 : 0;   // 1 = edges are int64
  }
}

__device__ __forceinline__ bf16 cvt_b(const void* src, int i, int f32m){
  if (f32m) return __float2bfloat16(((const float*)src)[i]);
  return ((const bf16*)src)[i];
}

// convert (weights+edges only) + histogram fused
__global__ __launch_bounds__(256) void k_convert(
    const void* __restrict__ W1,
    const void* __restrict__ as1,const void* __restrict__ ad1,
    const void* __restrict__ b1, const void* __restrict__ W2,
    const void* __restrict__ as2,const void* __restrict__ ad2,
    const void* __restrict__ b2, const void* __restrict__ ei,
    char* __restrict__ ws){
  const int* flags = (const int*)(ws + WS_FLAGS);
  int f32m = flags[0], i64m = flags[1];
  bf16* w1t  = (bf16*)(ws + WS_W1T);
  bf16* as1n = (bf16*)(ws + WS_AS1N);
  bf16* ad1n = (bf16*)(ws + WS_AD1N);
  bf16* b1n  = (bf16*)(ws + WS_B1N);
  bf16* w2t  = (bf16*)(ws + WS_W2T);
  bf16* as2n = (bf16*)(ws + WS_AS2N);
  bf16* ad2n = (bf16*)(ws + WS_AD2N);
  bf16* b2n  = (bf16*)(ws + WS_B2N);
  int*  es   = (int*) (ws + WS_ES);
  int*  ed   = (int*) (ws + WS_ED);
  int*  counts=(int*) (ws + WS_COUNTS);
  for (int g = blockIdx.x * 256 + threadIdx.x; g < CV_END; g += gridDim.x * 256){
    if      (g < CV_AS1){ int i = g-CV_W1; int k = i >> 8, n = i & 255;
      w1t[n*CIN + k] = cvt_b(W1, i, f32m); }                       // transpose
    else if (g < CV_AD1) as1n[g-CV_AS1] = cvt_b(as1,g-CV_AS1, f32m);
    else if (g < CV_B1 ) ad1n[g-CV_AD1] = cvt_b(ad1,g-CV_AD1, f32m);
    else if (g < CV_W2 ) b1n [g-CV_B1 ] = cvt_b(b1, g-CV_B1,  f32m);
    else if (g < CV_AS2){ int i = g-CV_W2; int k = i / NOUT, n = i - k*NOUT;
      w2t[n*CIN + k] = cvt_b(W2, i, f32m); }                       // transpose (rows 40..47 pre-zeroed)
    else if (g < CV_AD2) as2n[g-CV_AS2] = cvt_b(as2,g-CV_AS2, f32m);
    else if (g < CV_B2 ) ad2n[g-CV_AD2] = cvt_b(ad2,g-CV_AD2, f32m);
    else if (g < CV_ES ) b2n [g-CV_B2 ] = cvt_b(b2, g-CV_B2,  f32m);
    else if (g < CV_ED ){ int i = g-CV_ES;
      es[i] = i64m ? (int)((const long long*)ei)[i] : ((const int*)ei)[i]; }
    else               { int i = g-CV_ED;
      int d = i64m ? (int)((const long long*)ei)[(size_t)NE+i] : ((const int*)ei)[NE+i];
      ed[i] = d;
      atomicAdd(&counts[d], 1); }
  }
}

// ---------------- parallel CSR scan: part -> mid -> apply ----------------
__global__ __launch_bounds__(256) void k_scan_part(const int* __restrict__ counts, int* __restrict__ bsum){
  __shared__ int lds[256];
  int t = threadIdx.x;
  int idx = blockIdx.x * 256 + t;
  int v = (idx < NN) ? counts[idx] + 1 : 0;
  lds[t] = v;
  #pragma unroll
  for (int s = 128; s > 0; s >>= 1){
    __syncthreads();
    if (t < s) lds[t] += lds[t + s];
  }
  if (t == 0) bsum[blockIdx.x] = lds[0];
}

__global__ __launch_bounds__(256) void k_scan_mid(const int* __restrict__ bsum, int* __restrict__ boff,
                                                  int* __restrict__ row_ptr){
  __shared__ int lds[256];
  int t = threadIdx.x;
  int v = (t < SCB) ? bsum[t] : 0;
  lds[t] = v;
  for (int off = 1; off < 256; off <<= 1){
    __syncthreads();
    int u = (t >= off) ? lds[t - off] : 0;
    __syncthreads();
    lds[t] += u;
  }
  __syncthreads();
  if (t < SCB) boff[t] = lds[t] - v;   // exclusive
  if (t == 0) row_ptr[NN] = NETOT;     // total is a known constant
}

__global__ __launch_bounds__(256) void k_scan_apply(const int* __restrict__ counts, const int* __restrict__ boff,
                                                    int* __restrict__ row_ptr){
  __shared__ int lds[256];
  int t = threadIdx.x;
  int idx = blockIdx.x * 256 + t;
  int v = (idx < NN) ? counts[idx] + 1 : 0;
  lds[t] = v;
  for (int off = 1; off < 256; off <<= 1){
    __syncthreads();
    int u = (t >= off) ? lds[t - off] : 0;
    __syncthreads();
    lds[t] += u;
  }
  __syncthreads();
  if (idx < NN) row_ptr[idx] = boff[blockIdx.x] + lds[t] - v;
}

__global__ __launch_bounds__(256) void k_scatter(const int* __restrict__ es, const int* __restrict__ ed,
                                                 const int* __restrict__ row_ptr,
                                                 int* __restrict__ cursor, int* __restrict__ eidx,
                                                 int* __restrict__ dpos){
  int i = blockIdx.x * 256 + threadIdx.x;
  if (i >= NETOT) return;
  int s, d;
  if (i < NE){ s = es[i]; d = ed[i]; } else { s = i - NE; d = i - NE; }
  int pos = row_ptr[d] + atomicAdd(&cursor[d], 1);
  eidx[pos] = s;
  dpos[pos] = d;
}

// ---------------- GEMM1 (MFMA) + fused al1 + fp8 h1 store ---------------------
// Reads x directly in BOTH dtype modes (f32: float4 loads + in-register RNE
// bf16 cvt — numerically identical to the old convert+copy path).
// Register pipeline: full A row preloaded (8 chunks in flight), B double-buffered.
__global__ __launch_bounds__(256) void k_gemm1(const void* __restrict__ xin,
                                               const int* __restrict__ flags,
                                               const bf16* __restrict__ w1t,
                                               const bf16* __restrict__ as1, const bf16* __restrict__ ad1,
                                               unsigned char* __restrict__ h1q,
                                               float* __restrict__ al_s1, float* __restrict__ al_d1){
  int tid = threadIdx.x;
  int w = tid >> 6, lane = tid & 63, quad = lane >> 4, c = lane & 15;
  int row0 = blockIdx.x * 16;
  int n0 = w * 64;

  // ---- preload this lane's whole A row slice: 8 chunks x 8 bf16 ----
  v8s a[8];
  if (flags[0]){
    const float* xr = (const float*)xin + (size_t)(row0 + c) * CIN + quad * 8;
    #pragma unroll
    for (int i = 0; i < 8; ++i){
      float4 lo = *reinterpret_cast<const float4*>(xr + i * 32);
      float4 hi = *reinterpret_cast<const float4*>(xr + i * 32 + 4);
      v8s t;
      t[0] = (short)f2bits(lo.x); t[1] = (short)f2bits(lo.y);
      t[2] = (short)f2bits(lo.z); t[3] = (short)f2bits(lo.w);
      t[4] = (short)f2bits(hi.x); t[5] = (short)f2bits(hi.y);
      t[6] = (short)f2bits(hi.z); t[7] = (short)f2bits(hi.w);
      a[i] = t;
    }
  } else {
    const bf16* xr = (const bf16*)xin + (size_t)(row0 + c) * CIN + quad * 8;
    #pragma unroll
    for (int i = 0; i < 8; ++i) a[i] = *reinterpret_cast<const v8s*>(xr + i * 32);
  }

  v4f acc[4];
  #pragma unroll
  for (int t = 0; t < 4; ++t) acc[t] = (v4f){0.f, 0.f, 0.f, 0.f};

  const bf16* bbase = w1t + quad * 8;
  v8s bcur[4];
  #pragma unroll
  for (int t = 0; t < 4; ++t)
    bcur[t] = *reinterpret_cast<const v8s*>(bbase + (size_t)(n0 + t*16 + c) * CIN);
  #pragma unroll
  for (int k = 0; k < 8; ++k){
    v8s bnext[4];
    if (k < 7){
      #pragma unroll
      for (int t = 0; t < 4; ++t)
        bnext[t] = *reinterpret_cast<const v8s*>(bbase + (size_t)(n0 + t*16 + c) * CIN + (k+1)*32);
    }
    #pragma unroll
    for (int t = 0; t < 4; ++t)
      acc[t] = __builtin_amdgcn_mfma_f32_16x16x32_bf16(a[k], bcur[t], acc[t], 0, 0, 0);
    #pragma unroll
    for (int t = 0; t < 4; ++t) bcur[t] = bnext[t];
  }

  // fused al1: head w, channels t*16+c
  float as1v[4], ad1v[4];
  #pragma unroll
  for (int t = 0; t < 4; ++t){
    as1v[t] = b2f(as1[n0 + t*16 + c]);
    ad1v[t] = b2f(ad1[n0 + t*16 + c]);
  }
  #pragma unroll
  for (int r = 0; r < 4; ++r){
    float ps = 0.f, pd = 0.f;
    #pragma unroll
    for (int t = 0; t < 4; ++t){ ps += acc[t][r] * as1v[t]; pd += acc[t][r] * ad1v[t]; }
    #pragma unroll
    for (int off = 1; off < 16; off <<= 1){ ps += __shfl_xor(ps, off, 64); pd += __shfl_xor(pd, off, 64); }
    if (c == 0){
      int row = row0 + quad*4 + r;
      al_s1[row * NH + w] = ps;
      al_d1[row * NH + w] = pd;
    }
  }
  // fp8 h1 store
  #pragma unroll
  for (int t = 0; t < 4; ++t){
    #pragma unroll
    for (int r = 0; r < 4; r += 2){
      int pk = __builtin_amdgcn_cvt_pk_fp8_f32(acc[t][r], acc[t][r+1], 0, false);
      size_t col = n0 + t*16 + c;
      h1q[(size_t)(row0 + quad*4 + r    ) * HC + col] = (unsigned char)(pk & 0xFF);
      h1q[(size_t)(row0 + quad*4 + r + 1) * HC + col] = (unsigned char)((pk >> 8) & 0xFF);
    }
  }
}

// ---------------- edge weights layer 1 (edge-parallel, no chains) ----------------
__global__ __launch_bounds__(256) void k_ew1(const int* __restrict__ eidx, const int* __restrict__ dpos,
                                             const float* __restrict__ al_s1, const float* __restrict__ al_d1,
                                             float4* __restrict__ ew1){
  int p = blockIdx.x * 256 + threadIdx.x;
  if (p >= NETOT) return;
  int s = eidx[p], d = dpos[p];
  float4 as = reinterpret_cast<const float4*>(al_s1)[s];
  float4 ad = reinterpret_cast<const float4*>(al_d1)[d];
  float4 w;
  w.x = __expf(lrelu(as.x + ad.x));
  w.y = __expf(lrelu(as.y + ad.y));
  w.z = __expf(lrelu(as.z + ad.z));
  w.w = __expf(lrelu(as.w + ad.w));
  ew1[p] = w;
}

// ---------------- gather layer 1: precomputed weights, scalarized index stream ----
__global__ __launch_bounds__(256) void k_gather1(const int* __restrict__ row_ptr, const int* __restrict__ eidx,
                                                 const float* __restrict__ ew1,
                                                 const unsigned* __restrict__ h1v, const bf16* __restrict__ b1,
                                                 bf16* __restrict__ y1){
  int lane = threadIdx.x & 63;
  int n = blockIdx.x * 4 + (threadIdx.x >> 6);
  int h = lane >> 4;
  int p0 = __builtin_amdgcn_readfirstlane(row_ptr[n]);
  int p1 = __builtin_amdgcn_readfirstlane(row_ptr[n + 1]);
  float den = 0.f, a0 = 0.f, a1 = 0.f, a2 = 0.f, a3 = 0.f;
  int p = p0;
  for (; p + 1 < p1; p += 2){
    int sA = __builtin_amdgcn_readfirstlane(eidx[p]);
    int sB = __builtin_amdgcn_readfirstlane(eidx[p + 1]);
    float wA = ew1[(size_t)p * 4 + h];
    float wB = ew1[(size_t)(p + 1) * 4 + h];
    unsigned uA = h1v[(size_t)sA * 64 + lane];
    unsigned uB = h1v[(size_t)sB * 64 + lane];
    den += wA + wB;
    a0 += wA * __builtin_amdgcn_cvt_f32_fp8(uA, 0) + wB * __builtin_amdgcn_cvt_f32_fp8(uB, 0);
    a1 += wA * __builtin_amdgcn_cvt_f32_fp8(uA, 1) + wB * __builtin_amdgcn_cvt_f32_fp8(uB, 1);
    a2 += wA * __builtin_amdgcn_cvt_f32_fp8(uA, 2) + wB * __builtin_amdgcn_cvt_f32_fp8(uB, 2);
    a3 += wA * __builtin_amdgcn_cvt_f32_fp8(uA, 3) + wB * __builtin_amdgcn_cvt_f32_fp8(uB, 3);
  }
  if (p < p1){
    int s = __builtin_amdgcn_readfirstlane(eidx[p]);
    float w = ew1[(size_t)p * 4 + h];
    unsigned u = h1v[(size_t)s * 64 + lane];
    den += w;
    a0 += w * __builtin_amdgcn_cvt_f32_fp8(u, 0);
    a1 += w * __builtin_amdgcn_cvt_f32_fp8(u, 1);
    a2 += w * __builtin_amdgcn_cvt_f32_fp8(u, 2);
    a3 += w * __builtin_amdgcn_cvt_f32_fp8(u, 3);
  }
  float inv = 1.f / (den + 1e-16f);
  ushort4 bb = reinterpret_cast<const ushort4*>(b1)[lane];
  ushort4 o;
  o.x = f2bits(fmaxf(a0 * inv + bits2f(bb.x), 0.f));
  o.y = f2bits(fmaxf(a1 * inv + bits2f(bb.y), 0.f));
  o.z = f2bits(fmaxf(a2 * inv + bits2f(bb.z), 0.f));
  o.w = f2bits(fmaxf(a3 * inv + bits2f(bb.w), 0.f));
  reinterpret_cast<ushort4*>(y1)[(size_t)n * 64 + lane] = o;
}

// ---------------- GEMM2 (MFMA) + fused al_s2/al_d2 ----------------
__global__ __launch_bounds__(256) void k_gemm2(const bf16* __restrict__ y1, const bf16* __restrict__ w2t,
                                               const bf16* __restrict__ as2, const bf16* __restrict__ ad2,
                                               bf16* __restrict__ h2, float* __restrict__ al_s2,
                                               float* __restrict__ al_d2){
  int tid = threadIdx.x;
  int w = tid >> 6, lane = tid & 63, quad = lane >> 4, c = lane & 15;
  int m0 = blockIdx.x * 64 + w * 16;
  v4f acc[3];
  #pragma unroll
  for (int t = 0; t < 3; ++t) acc[t] = (v4f){0.f, 0.f, 0.f, 0.f};
  const bf16* arow = y1 + (size_t)(m0 + c) * HC + quad * 8;   // OOB rows read ws scratch; stores guarded
  #pragma unroll
  for (int k0 = 0; k0 < 256; k0 += 32){
    v8s a = *reinterpret_cast<const v8s*>(arow + k0);
    #pragma unroll
    for (int t = 0; t < 3; ++t){
      v8s b = *reinterpret_cast<const v8s*>(w2t + (size_t)(t*16 + c) * CIN + quad * 8 + k0);
      acc[t] = __builtin_amdgcn_mfma_f32_16x16x32_bf16(a, b, acc[t], 0, 0, 0);
    }
  }
  float as2f[3], ad2f[3];
  #pragma unroll
  for (int t = 0; t < 3; ++t){
    int col = t*16 + c;
    as2f[t] = (col < NOUT) ? b2f(as2[col]) : 0.f;
    ad2f[t] = (col < NOUT) ? b2f(ad2[col]) : 0.f;
  }
  #pragma unroll
  for (int r = 0; r < 4; ++r){
    int row = m0 + quad*4 + r;
    float ps = 0.f, pd = 0.f;
    #pragma unroll
    for (int t = 0; t < 3; ++t){ ps += acc[t][r] * as2f[t]; pd += acc[t][r] * ad2f[t]; }
    #pragma unroll
    for (int off = 1; off < 16; off <<= 1){ ps += __shfl_xor(ps, off, 64); pd += __shfl_xor(pd, off, 64); }
    if (row < NN){
      if (c == 0){ al_s2[row] = ps; al_d2[row] = pd; }
      #pragma unroll
      for (int t = 0; t < 3; ++t){
        int col = t*16 + c;
        if (col < NOUT) h2[(size_t)row * NOUT + col] = f2b(acc[t][r]);
      }
    }
  }
}

// ---------------- edge weights layer 2 (edge-parallel) ----------------
__global__ __launch_bounds__(256) void k_ew2(const int* __restrict__ eidx, const int* __restrict__ dpos,
                                             const float* __restrict__ al_s2, const float* __restrict__ al_d2,
                                             float* __restrict__ ew2){
  int p = blockIdx.x * 256 + threadIdx.x;
  if (p >= NETOT) return;
  ew2[p] = __expf(lrelu(al_s2[eidx[p]] + al_d2[dpos[p]]));
}

// ---------------- gather layer 2 + bias + log_softmax ----------------
__global__ __launch_bounds__(256) void k_gather2(const int* __restrict__ row_ptr, const int* __restrict__ eidx,
                                                 const float* __restrict__ ew2,
                                                 const bf16* __restrict__ h2, const bf16* __restrict__ b2v,
                                                 const int* __restrict__ flags, void* __restrict__ out){
  int lane = threadIdx.x & 63;
  int n = blockIdx.x * 4 + (threadIdx.x >> 6);
  int p0 = __builtin_amdgcn_readfirstlane(row_ptr[n]);
  int p1 = __builtin_amdgcn_readfirstlane(row_ptr[n + 1]);
  float den = 0.f, acc = 0.f;
  int p = p0;
  for (; p + 1 < p1; p += 2){
    int sA = __builtin_amdgcn_readfirstlane(eidx[p]);
    int sB = __builtin_amdgcn_readfirstlane(eidx[p + 1]);
    float wA = ew2[p], wB = ew2[p + 1];
    float hA = 0.f, hB = 0.f;
    if (lane < NOUT){
      hA = b2f(h2[(size_t)sA * NOUT + lane]);
      hB = b2f(h2[(size_t)sB * NOUT + lane]);
    }
    den += wA + wB;
    acc += wA * hA + wB * hB;
  }
  if (p < p1){
    int s = __builtin_amdgcn_readfirstlane(eidx[p]);
    float w = ew2[p];
    den += w;
    if (lane < NOUT) acc += w * b2f(h2[(size_t)s * NOUT + lane]);
  }
  float v = (lane < NOUT) ? (acc / (den + 1e-16f) + b2f(b2v[lane])) : -INFINITY;
  float M = wave_max(v);
  float ex = (lane < NOUT) ? __expf(v - M) : 0.f;
  float S = wave_sum(ex);
  if (lane < NOUT){
    float r = v - M - __logf(S);
    size_t idx = (size_t)n * NOUT + lane;
    if (flags[0]) ((float*)out)[idx] = r;
    else          ((bf16*)out)[idx]  = f2b(r);
  }
}

extern "C" void kernel_launch(void* const* d_in, const int* in_sizes, int n_in,
                              void* d_out, int out_size, void* d_ws, size_t ws_size,
                              hipStream_t stream) {
  const void* x   = d_in[0];
  const void* ei  = d_in[1];
  const void* W1  = d_in[2];
  const void* as1 = d_in[3];
  const void* ad1 = d_in[4];
  const void* b1  = d_in[5];
  const void* W2  = d_in[6];
  const void* as2 = d_in[7];
  const void* ad2 = d_in[8];
  const void* b2  = d_in[9];

  char* ws = (char*)d_ws;
  int*   flags   = (int*)  (ws + WS_FLAGS);
  float* ew1     = (float*)(ws + WS_EW1);
  bf16*  w1t     = (bf16*) (ws + WS_W1T);
  bf16*  as1n    = (bf16*) (ws + WS_AS1N);
  bf16*  ad1n    = (bf16*) (ws + WS_AD1N);
  bf16*  b1n     = (bf16*) (ws + WS_B1N);
  bf16*  w2t     = (bf16*) (ws + WS_W2T);
  bf16*  as2n    = (bf16*) (ws + WS_AS2N);
  bf16*  ad2n    = (bf16*) (ws + WS_AD2N);
  bf16*  b2n     = (bf16*) (ws + WS_B2N);
  int*   es      = (int*)  (ws + WS_ES);
  int*   ed      = (int*)  (ws + WS_ED);
  int*   counts  = (int*)  (ws + WS_COUNTS);
  int*   cursor  = (int*)  (ws + WS_CURSOR);
  int*   row_ptr = (int*)  (ws + WS_ROWPTR);
  int*   eidx    = (int*)  (ws + WS_EIDX);
  int*   dpos    = (int*)  (ws + WS_DPOS);
  unsigned char* h1q = (unsigned char*)(ws + WS_H1);
  float* al_s1   = (float*)(ws + WS_ALS1);
  float* al_d1   = (float*)(ws + WS_ALD1);
  bf16*  y1      = (bf16*) (ws + WS_Y1);
  bf16*  h2      = (bf16*) (ws + WS_H2);
  float* al_s2   = (float*)(ws + WS_ALS2);
  float* al_d2   = (float*)(ws + WS_ALD2);
  float* ew2     = (float*)(ws + WS_EW2);
  int*   bsum    = (int*)  (ws + WS_BSUM);
  int*   boff    = (int*)  (ws + WS_BOFF);

  hipMemsetAsync(counts, 0, (size_t)NN * 4, stream);
  hipMemsetAsync(cursor, 0, (size_t)NN * 4, stream);
  hipMemsetAsync(w2t,    0, (size_t)NPAD * CIN * 2, stream);

  k_detect <<<1, 64, 0, stream>>>((const unsigned short*)x, (const unsigned*)ei, flags);
  k_convert<<<1024, 256, 0, stream>>>(W1, as1, ad1, b1, W2, as2, ad2, b2, ei, ws);

  int eb = (NETOT + 255) / 256;
  k_scan_part <<<SCB, 256, 0, stream>>>(counts, bsum);
  k_scan_mid  <<<1, 256, 0, stream>>>(bsum, boff, row_ptr);
  k_scan_apply<<<SCB, 256, 0, stream>>>(counts, boff, row_ptr);
  k_scatter<<<eb, 256, 0, stream>>>(es, ed, row_ptr, cursor, eidx, dpos);

  k_gemm1  <<<NN / 16, 256, 0, stream>>>(x, flags, w1t, as1n, ad1n, h1q, al_s1, al_d1);
  k_ew1    <<<eb, 256, 0, stream>>>(eidx, dpos, al_s1, al_d1, (float4*)ew1);
  k_gather1<<<NN / 4, 256, 0, stream>>>(row_ptr, eidx, ew1, (const unsigned*)h1q, b1n, y1);
  k_gemm2  <<<(NN + 63) / 64, 256, 0, stream>>>(y1, w2t, as2n, ad2n, h2, al_s2, al_d2);
  k_ew2    <<<eb, 256, 0, stream>>>(eidx, dpos, al_s2, al_d2, ew2);
  k_gather2<<<NN / 4, 256, 0, stream>>>(row_ptr, eidx, ew2, h2, b2n, flags, d_out);
}

// Round 9
// 346.960 us; speedup vs baseline: 1.1328x; 1.1328x over previous
//
#include <hip/hip_runtime.h>
#include <hip/hip_bf16.h>

typedef __hip_bfloat16 bf16;
typedef short v8s __attribute__((ext_vector_type(8)));   // 8 bf16 (4 VGPRs), MFMA A/B frag
typedef float v4f __attribute__((ext_vector_type(4)));   // MFMA C/D frag

constexpr int NN    = 50000;   // nodes
constexpr int NE    = 800000;  // raw edges
constexpr int NETOT = 850000;  // + self loops
constexpr int CIN   = 256;
constexpr int HC    = 256;     // H*C
constexpr int NH    = 4;
constexpr int NOUT  = 40;
constexpr int NPAD  = 48;      // W2T padded cols (3 x 16)
constexpr int SCB   = 196;     // scan blocks (196*256 >= NN)

// ---------------- workspace layout ----------------
constexpr size_t al256(size_t x){ return (x + 255) & ~(size_t)255; }
constexpr size_t WS_FLAGS = 0;                                   // 2 ints
constexpr size_t WS_EW1   = 256;                                 // NETOT float4
constexpr size_t WS_W1T   = al256(WS_EW1   + (size_t)NETOT*16);  // [n][k] 256x256 bf16
constexpr size_t WS_AS1N  = al256(WS_W1T   + (size_t)CIN*HC*2);
constexpr size_t WS_AD1N  = al256(WS_AS1N  + HC*2);
constexpr size_t WS_B1N   = al256(WS_AD1N  + HC*2);
constexpr size_t WS_W2T   = al256(WS_B1N   + HC*2);              // [n][k] 48x256 bf16 (zero-padded)
constexpr size_t WS_AS2N  = al256(WS_W2T   + (size_t)NPAD*HC*2);
constexpr size_t WS_AD2N  = al256(WS_AS2N  + NOUT*2);
constexpr size_t WS_B2N   = al256(WS_AD2N  + NOUT*2);
constexpr size_t WS_ES    = al256(WS_B2N   + NOUT*2);            // NE int32
constexpr size_t WS_ED    = al256(WS_ES    + (size_t)NE*4);
constexpr size_t WS_COUNTS= al256(WS_ED    + (size_t)NE*4);
constexpr size_t WS_CURSOR= al256(WS_COUNTS+ (size_t)NN*4);
constexpr size_t WS_ROWPTR= al256(WS_CURSOR+ (size_t)NN*4);
constexpr size_t WS_EIDX  = al256(WS_ROWPTR+ (size_t)(NN+1)*4);
constexpr size_t WS_DPOS  = al256(WS_EIDX  + (size_t)NETOT*4);   // NETOT int32 (dst per CSR slot)
constexpr size_t WS_H1    = al256(WS_DPOS  + (size_t)NETOT*4);   // NN*HC fp8 (1B)
constexpr size_t WS_ALS1  = al256(WS_H1    + (size_t)NN*HC);
constexpr size_t WS_ALD1  = al256(WS_ALS1  + (size_t)NN*NH*4);
constexpr size_t WS_Y1    = al256(WS_ALD1  + (size_t)NN*NH*4);   // NN*HC bf16
constexpr size_t WS_H2    = al256(WS_Y1    + (size_t)NN*HC*2);   // NN*NOUT bf16
constexpr size_t WS_ALS2  = al256(WS_H2    + (size_t)NN*NOUT*2);
constexpr size_t WS_ALD2  = al256(WS_ALS2  + (size_t)NN*4);
constexpr size_t WS_EW2   = al256(WS_ALD2  + (size_t)NN*4);      // NETOT float
constexpr size_t WS_BSUM  = al256(WS_EW2   + (size_t)NETOT*4);   // 256 int
constexpr size_t WS_BOFF  = al256(WS_BSUM  + 1024);              // 256 int

// ---------------- convert virtual index space (x handled in gemm1) ---------
constexpr int CV_W1  = 0;
constexpr int CV_AS1 = CV_W1  + CIN*HC;
constexpr int CV_AD1 = CV_AS1 + HC;
constexpr int CV_B1  = CV_AD1 + HC;
constexpr int CV_W2  = CV_B1  + HC;
constexpr int CV_AS2 = CV_W2  + HC*NOUT;
constexpr int CV_AD2 = CV_AS2 + NOUT;
constexpr int CV_B2  = CV_AD2 + NOUT;
constexpr int CV_ES  = CV_B2  + NOUT;
constexpr int CV_ED  = CV_ES  + NE;
constexpr int CV_END = CV_ED  + NE;

__device__ __forceinline__ float b2f(bf16 v) { return __bfloat162float(v); }
__device__ __forceinline__ bf16  f2b(float v){ return __float2bfloat16(v); }
__device__ __forceinline__ float bits2f(unsigned short u){ return __uint_as_float(((unsigned)u) << 16); }
__device__ __forceinline__ unsigned short f2bits(float v){
  bf16 t = __float2bfloat16(v);
  return *reinterpret_cast<unsigned short*>(&t);
}
__device__ __forceinline__ float lrelu(float x){ return x > 0.f ? x : 0.2f * x; }

__device__ __forceinline__ float wave_sum(float v){
  #pragma unroll
  for (int off = 32; off; off >>= 1) v += __shfl_xor(v, off, 64);
  return v;
}
__device__ __forceinline__ float wave_max(float v){
  #pragma unroll
  for (int off = 32; off; off >>= 1) v = fmaxf(v, __shfl_xor(v, off, 64));
  return v;
}

// ---------------- dtype detection ----------------
__global__ __launch_bounds__(64) void k_detect(const unsigned short* __restrict__ xu,
                                               const unsigned* __restrict__ eu,
                                               int* __restrict__ flags){
  int lane = threadIdx.x;
  int cnt = 0;
  for (int i = lane; i < 256; i += 64){
    int e = (xu[i] >> 7) & 0xFF;
    cnt += (e >= 0x60 && e <= 0x8F) ? 1 : 0;
  }
  #pragma unroll
  for (int off = 32; off; off >>= 1) cnt += __shfl_xor(cnt, off, 64);
  unsigned odd = eu[2 * lane + 1];
  #pragma unroll
  for (int off = 32; off; off >>= 1) odd |= __shfl_xor(odd, off, 64);
  if (lane == 0){
    flags[0] = (cnt < 218) ? 1 : 0;   // 1 = floats are f32
    flags[1] = (odd == 0)  ? 1 : 0;   // 1 = edges are int64
  }
}

__device__ __forceinline__ bf16 cvt_b(const void* src, int i, int f32m){
  if (f32m) return __float2bfloat16(((const float*)src)[i]);
  return ((const bf16*)src)[i];
}

// convert (weights+edges only) + histogram fused
__global__ __launch_bounds__(256) void k_convert(
    const void* __restrict__ W1,
    const void* __restrict__ as1,const void* __restrict__ ad1,
    const void* __restrict__ b1, const void* __restrict__ W2,
    const void* __restrict__ as2,const void* __restrict__ ad2,
    const void* __restrict__ b2, const void* __restrict__ ei,
    char* __restrict__ ws){
  const int* flags = (const int*)(ws + WS_FLAGS);
  int f32m = flags[0], i64m = flags[1];
  bf16* w1t  = (bf16*)(ws + WS_W1T);
  bf16* as1n = (bf16*)(ws + WS_AS1N);
  bf16* ad1n = (bf16*)(ws + WS_AD1N);
  bf16* b1n  = (bf16*)(ws + WS_B1N);
  bf16* w2t  = (bf16*)(ws + WS_W2T);
  bf16* as2n = (bf16*)(ws + WS_AS2N);
  bf16* ad2n = (bf16*)(ws + WS_AD2N);
  bf16* b2n  = (bf16*)(ws + WS_B2N);
  int*  es   = (int*) (ws + WS_ES);
  int*  ed   = (int*) (ws + WS_ED);
  int*  counts=(int*) (ws + WS_COUNTS);
  for (int g = blockIdx.x * 256 + threadIdx.x; g < CV_END; g += gridDim.x * 256){
    if      (g < CV_AS1){ int i = g-CV_W1; int k = i >> 8, n = i & 255;
      w1t[n*CIN + k] = cvt_b(W1, i, f32m); }                       // transpose
    else if (g < CV_AD1) as1n[g-CV_AS1] = cvt_b(as1,g-CV_AS1, f32m);
    else if (g < CV_B1 ) ad1n[g-CV_AD1] = cvt_b(ad1,g-CV_AD1, f32m);
    else if (g < CV_W2 ) b1n [g-CV_B1 ] = cvt_b(b1, g-CV_B1,  f32m);
    else if (g < CV_AS2){ int i = g-CV_W2; int k = i / NOUT, n = i - k*NOUT;
      w2t[n*CIN + k] = cvt_b(W2, i, f32m); }                       // transpose (rows 40..47 pre-zeroed)
    else if (g < CV_AD2) as2n[g-CV_AS2] = cvt_b(as2,g-CV_AS2, f32m);
    else if (g < CV_B2 ) ad2n[g-CV_AD2] = cvt_b(ad2,g-CV_AD2, f32m);
    else if (g < CV_ES ) b2n [g-CV_B2 ] = cvt_b(b2, g-CV_B2,  f32m);
    else if (g < CV_ED ){ int i = g-CV_ES;
      es[i] = i64m ? (int)((const long long*)ei)[i] : ((const int*)ei)[i]; }
    else               { int i = g-CV_ED;
      int d = i64m ? (int)((const long long*)ei)[(size_t)NE+i] : ((const int*)ei)[NE+i];
      ed[i] = d;
      atomicAdd(&counts[d], 1); }
  }
}

// ---------------- parallel CSR scan ----------------
__global__ __launch_bounds__(256) void k_scan_part(const int* __restrict__ counts, int* __restrict__ bsum){
  __shared__ int lds[256];
  int t = threadIdx.x;
  int idx = blockIdx.x * 256 + t;
  int v = (idx < NN) ? counts[idx] + 1 : 0;
  lds[t] = v;
  #pragma unroll
  for (int s = 128; s > 0; s >>= 1){
    __syncthreads();
    if (t < s) lds[t] += lds[t + s];
  }
  if (t == 0) bsum[blockIdx.x] = lds[0];
}

__global__ __launch_bounds__(256) void k_scan_mid(const int* __restrict__ bsum, int* __restrict__ boff,
                                                  int* __restrict__ row_ptr){
  __shared__ int lds[256];
  int t = threadIdx.x;
  int v = (t < SCB) ? bsum[t] : 0;
  lds[t] = v;
  for (int off = 1; off < 256; off <<= 1){
    __syncthreads();
    int u = (t >= off) ? lds[t - off] : 0;
    __syncthreads();
    lds[t] += u;
  }
  __syncthreads();
  if (t < SCB) boff[t] = lds[t] - v;   // exclusive
  if (t == 0) row_ptr[NN] = NETOT;
}

__global__ __launch_bounds__(256) void k_scan_apply(const int* __restrict__ counts, const int* __restrict__ boff,
                                                    int* __restrict__ row_ptr){
  __shared__ int lds[256];
  int t = threadIdx.x;
  int idx = blockIdx.x * 256 + t;
  int v = (idx < NN) ? counts[idx] + 1 : 0;
  lds[t] = v;
  for (int off = 1; off < 256; off <<= 1){
    __syncthreads();
    int u = (t >= off) ? lds[t - off] : 0;
    __syncthreads();
    lds[t] += u;
  }
  __syncthreads();
  if (idx < NN) row_ptr[idx] = boff[blockIdx.x] + lds[t] - v;
}

__global__ __launch_bounds__(256) void k_scatter(const int* __restrict__ es, const int* __restrict__ ed,
                                                 const int* __restrict__ row_ptr,
                                                 int* __restrict__ cursor, int* __restrict__ eidx,
                                                 int* __restrict__ dpos){
  int i = blockIdx.x * 256 + threadIdx.x;
  if (i >= NETOT) return;
  int s, d;
  if (i < NE){ s = es[i]; d = ed[i]; } else { s = i - NE; d = i - NE; }
  int pos = row_ptr[d] + atomicAdd(&cursor[d], 1);
  eidx[pos] = s;
  dpos[pos] = d;
}

// ---------------- GEMM1 (MFMA, LDS-staged) + fused al1 + fp8 h1 store ---------
// Block: 64 rows x 256 cols; wave w: 64 rows x cols [w*64, w*64+64) == head w.
// K in 4 phases of 64. A,B staged in LDS (pad rows to 72 elems -> conflict-free
// ds_read_b128). Staging loads are independent -> full ILP, no scheduler fight.
constexpr int G1R = 64;                 // rows per block
constexpr int LP  = 72;                 // padded LDS row (elems)
__global__ __launch_bounds__(256) void k_gemm1(const void* __restrict__ xin,
                                               const int* __restrict__ flags,
                                               const bf16* __restrict__ w1t,
                                               const bf16* __restrict__ as1, const bf16* __restrict__ ad1,
                                               unsigned char* __restrict__ h1q,
                                               float* __restrict__ al_s1, float* __restrict__ al_d1){
  __shared__ short Ab[G1R * LP];        //  9216 shorts
  __shared__ short Bb[256 * LP];        // 18432 shorts  (total 55 KB? no: 27648 shorts = 55296 B)
  int tid  = threadIdx.x;
  int w    = tid >> 6, lane = tid & 63, quad = lane >> 4, c = lane & 15;
  int row0 = blockIdx.x * G1R;
  int f32m = flags[0];

  v4f acc[4][4];
  #pragma unroll
  for (int mt = 0; mt < 4; ++mt)
    #pragma unroll
    for (int nt = 0; nt < 4; ++nt) acc[mt][nt] = (v4f){0.f,0.f,0.f,0.f};

  int arow = tid >> 2;                  // 0..63
  int aseg = tid & 3;                   // 0..3 (16 elems each)
  int grow = row0 + arow; if (grow >= NN) grow = NN - 1;

  for (int ph = 0; ph < 4; ++ph){
    if (ph) __syncthreads();
    // ---- stage A: 64 rows x 64 k (16 elems/thread) ----
    {
      short va[16];
      if (f32m){
        const float* src = (const float*)xin + (size_t)grow * CIN + ph*64 + aseg*16;
        #pragma unroll
        for (int i = 0; i < 4; ++i){
          float4 f = *reinterpret_cast<const float4*>(src + i*4);
          va[i*4+0] = (short)f2bits(f.x); va[i*4+1] = (short)f2bits(f.y);
          va[i*4+2] = (short)f2bits(f.z); va[i*4+3] = (short)f2bits(f.w);
        }
      } else {
        const short* src = (const short*)xin + (size_t)grow * CIN + ph*64 + aseg*16;
        v8s u0 = *reinterpret_cast<const v8s*>(src);
        v8s u1 = *reinterpret_cast<const v8s*>(src + 8);
        #pragma unroll
        for (int i = 0; i < 8; ++i){ va[i] = u0[i]; va[8+i] = u1[i]; }
      }
      short* dst = &Ab[arow * LP + aseg * 16];
      *reinterpret_cast<v8s*>(dst)     = *reinterpret_cast<v8s*>(&va[0]);
      *reinterpret_cast<v8s*>(dst + 8) = *reinterpret_cast<v8s*>(&va[8]);
    }
    // ---- stage B: 256 n-rows x 64 k (1 row/thread) ----
    {
      const short* src = (const short*)w1t + (size_t)tid * CIN + ph*64;
      short* dst = &Bb[tid * LP];
      #pragma unroll
      for (int j = 0; j < 8; ++j)
        *reinterpret_cast<v8s*>(dst + j*8) = *reinterpret_cast<const v8s*>(src + j*8);
    }
    __syncthreads();
    // ---- compute: 2 k-steps of 32 ----
    #pragma unroll
    for (int s = 0; s < 2; ++s){
      int ch = s*4 + quad;
      v8s af[4], bf[4];
      #pragma unroll
      for (int mt = 0; mt < 4; ++mt)
        af[mt] = *reinterpret_cast<const v8s*>(&Ab[(mt*16 + c) * LP + ch*8]);
      #pragma unroll
      for (int nt = 0; nt < 4; ++nt)
        bf[nt] = *reinterpret_cast<const v8s*>(&Bb[(w*64 + nt*16 + c) * LP + ch*8]);
      #pragma unroll
      for (int mt = 0; mt < 4; ++mt)
        #pragma unroll
        for (int nt = 0; nt < 4; ++nt)
          acc[mt][nt] = __builtin_amdgcn_mfma_f32_16x16x32_bf16(af[mt], bf[nt], acc[mt][nt], 0, 0, 0);
    }
  }

  // ---- fused al1 (head w) ----
  float as1v[4], ad1v[4];
  #pragma unroll
  for (int nt = 0; nt < 4; ++nt){
    as1v[nt] = b2f(as1[w*64 + nt*16 + c]);
    ad1v[nt] = b2f(ad1[w*64 + nt*16 + c]);
  }
  #pragma unroll
  for (int mt = 0; mt < 4; ++mt){
    #pragma unroll
    for (int r = 0; r < 4; ++r){
      float ps = 0.f, pd = 0.f;
      #pragma unroll
      for (int nt = 0; nt < 4; ++nt){ ps += acc[mt][nt][r] * as1v[nt]; pd += acc[mt][nt][r] * ad1v[nt]; }
      #pragma unroll
      for (int off = 1; off < 16; off <<= 1){ ps += __shfl_xor(ps, off, 64); pd += __shfl_xor(pd, off, 64); }
      int row = row0 + mt*16 + quad*4 + r;
      if (c == 0 && row < NN){
        al_s1[row * NH + w] = ps;
        al_d1[row * NH + w] = pd;
      }
    }
  }
  // ---- fp8 h1 store ----
  #pragma unroll
  for (int mt = 0; mt < 4; ++mt){
    #pragma unroll
    for (int nt = 0; nt < 4; ++nt){
      #pragma unroll
      for (int r = 0; r < 4; r += 2){
        int row = row0 + mt*16 + quad*4 + r;
        if (row + 1 < NN){
          int pk = __builtin_amdgcn_cvt_pk_fp8_f32(acc[mt][nt][r], acc[mt][nt][r+1], 0, false);
          size_t col = w*64 + nt*16 + c;
          h1q[(size_t)row       * HC + col] = (unsigned char)(pk & 0xFF);
          h1q[(size_t)(row + 1) * HC + col] = (unsigned char)((pk >> 8) & 0xFF);
        } else if (row < NN){
          int pk = __builtin_amdgcn_cvt_pk_fp8_f32(acc[mt][nt][r], acc[mt][nt][r], 0, false);
          h1q[(size_t)row * HC + w*64 + nt*16 + c] = (unsigned char)(pk & 0xFF);
        }
      }
    }
  }
}

// ---------------- edge weights layer 1 ----------------
__global__ __launch_bounds__(256) void k_ew1(const int* __restrict__ eidx, const int* __restrict__ dpos,
                                             const float* __restrict__ al_s1, const float* __restrict__ al_d1,
                                             float4* __restrict__ ew1){
  int p = blockIdx.x * 256 + threadIdx.x;
  if (p >= NETOT) return;
  int s = eidx[p], d = dpos[p];
  float4 as = reinterpret_cast<const float4*>(al_s1)[s];
  float4 ad = reinterpret_cast<const float4*>(al_d1)[d];
  float4 w;
  w.x = __expf(lrelu(as.x + ad.x));
  w.y = __expf(lrelu(as.y + ad.y));
  w.z = __expf(lrelu(as.z + ad.z));
  w.w = __expf(lrelu(as.w + ad.w));
  ew1[p] = w;
}

// ---------------- gather layer 1 ----------------
__global__ __launch_bounds__(256) void k_gather1(const int* __restrict__ row_ptr, const int* __restrict__ eidx,
                                                 const float* __restrict__ ew1,
                                                 const unsigned* __restrict__ h1v, const bf16* __restrict__ b1,
                                                 bf16* __restrict__ y1){
  int lane = threadIdx.x & 63;
  int n = blockIdx.x * 4 + (threadIdx.x >> 6);
  int h = lane >> 4;
  int p0 = __builtin_amdgcn_readfirstlane(row_ptr[n]);
  int p1 = __builtin_amdgcn_readfirstlane(row_ptr[n + 1]);
  float den = 0.f, a0 = 0.f, a1 = 0.f, a2 = 0.f, a3 = 0.f;
  int p = p0;
  for (; p + 1 < p1; p += 2){
    int sA = __builtin_amdgcn_readfirstlane(eidx[p]);
    int sB = __builtin_amdgcn_readfirstlane(eidx[p + 1]);
    float wA = ew1[(size_t)p * 4 + h];
    float wB = ew1[(size_t)(p + 1) * 4 + h];
    unsigned uA = h1v[(size_t)sA * 64 + lane];
    unsigned uB = h1v[(size_t)sB * 64 + lane];
    den += wA + wB;
    a0 += wA * __builtin_amdgcn_cvt_f32_fp8(uA, 0) + wB * __builtin_amdgcn_cvt_f32_fp8(uB, 0);
    a1 += wA * __builtin_amdgcn_cvt_f32_fp8(uA, 1) + wB * __builtin_amdgcn_cvt_f32_fp8(uB, 1);
    a2 += wA * __builtin_amdgcn_cvt_f32_fp8(uA, 2) + wB * __builtin_amdgcn_cvt_f32_fp8(uB, 2);
    a3 += wA * __builtin_amdgcn_cvt_f32_fp8(uA, 3) + wB * __builtin_amdgcn_cvt_f32_fp8(uB, 3);
  }
  if (p < p1){
    int s = __builtin_amdgcn_readfirstlane(eidx[p]);
    float w = ew1[(size_t)p * 4 + h];
    unsigned u = h1v[(size_t)s * 64 + lane];
    den += w;
    a0 += w * __builtin_amdgcn_cvt_f32_fp8(u, 0);
    a1 += w * __builtin_amdgcn_cvt_f32_fp8(u, 1);
    a2 += w * __builtin_amdgcn_cvt_f32_fp8(u, 2);
    a3 += w * __builtin_amdgcn_cvt_f32_fp8(u, 3);
  }
  float inv = 1.f / (den + 1e-16f);
  ushort4 bb = reinterpret_cast<const ushort4*>(b1)[lane];
  ushort4 o;
  o.x = f2bits(fmaxf(a0 * inv + bits2f(bb.x), 0.f));
  o.y = f2bits(fmaxf(a1 * inv + bits2f(bb.y), 0.f));
  o.z = f2bits(fmaxf(a2 * inv + bits2f(bb.z), 0.f));
  o.w = f2bits(fmaxf(a3 * inv + bits2f(bb.w), 0.f));
  reinterpret_cast<ushort4*>(y1)[(size_t)n * 64 + lane] = o;
}

// ---------------- GEMM2 (MFMA, W2T in LDS) + fused al_s2/al_d2 ----------------
constexpr int W2LP = 260;   // padded LDS row (elems) for W2T
__global__ __launch_bounds__(256) void k_gemm2(const bf16* __restrict__ y1, const bf16* __restrict__ w2t,
                                               const bf16* __restrict__ as2, const bf16* __restrict__ ad2,
                                               bf16* __restrict__ h2, float* __restrict__ al_s2,
                                               float* __restrict__ al_d2){
  __shared__ short Wb[NPAD * W2LP];     // 48 x 260 shorts = 24.4 KB
  int tid = threadIdx.x;
  int w = tid >> 6, lane = tid & 63, quad = lane >> 4, c = lane & 15;
  int m0 = blockIdx.x * 64 + w * 16;
  // stage W2T: 48 rows x 32 segs of 16B
  for (int idx = tid; idx < NPAD * 32; idx += 256){
    int n = idx >> 5, sg = idx & 31;
    *reinterpret_cast<v8s*>(&Wb[n * W2LP + sg * 8]) =
      *reinterpret_cast<const v8s*>((const short*)w2t + (size_t)n * CIN + sg * 8);
  }
  // A preload: whole row (8 chunks), independent loads
  int arow = m0 + c; if (arow >= NN) arow = NN - 1;
  const short* ar = (const short*)y1 + (size_t)arow * HC + quad * 8;
  v8s a[8];
  #pragma unroll
  for (int i = 0; i < 8; ++i) a[i] = *reinterpret_cast<const v8s*>(ar + i * 32);
  __syncthreads();

  v4f acc[3];
  #pragma unroll
  for (int t = 0; t < 3; ++t) acc[t] = (v4f){0.f, 0.f, 0.f, 0.f};
  #pragma unroll
  for (int k = 0; k < 8; ++k){
    int ch = k*4 + quad;
    #pragma unroll
    for (int t = 0; t < 3; ++t){
      v8s b = *reinterpret_cast<const v8s*>(&Wb[(t*16 + c) * W2LP + ch * 8]);
      acc[t] = __builtin_amdgcn_mfma_f32_16x16x32_bf16(a[k], b, acc[t], 0, 0, 0);
    }
  }
  float as2f[3], ad2f[3];
  #pragma unroll
  for (int t = 0; t < 3; ++t){
    int col = t*16 + c;
    as2f[t] = (col < NOUT) ? b2f(as2[col]) : 0.f;
    ad2f[t] = (col < NOUT) ? b2f(ad2[col]) : 0.f;
  }
  #pragma unroll
  for (int r = 0; r < 4; ++r){
    int row = m0 + quad*4 + r;
    float ps = 0.f, pd = 0.f;
    #pragma unroll
    for (int t = 0; t < 3; ++t){ ps += acc[t][r] * as2f[t]; pd += acc[t][r] * ad2f[t]; }
    #pragma unroll
    for (int off = 1; off < 16; off <<= 1){ ps += __shfl_xor(ps, off, 64); pd += __shfl_xor(pd, off, 64); }
    if (row < NN){
      if (c == 0){ al_s2[row] = ps; al_d2[row] = pd; }
      #pragma unroll
      for (int t = 0; t < 3; ++t){
        int col = t*16 + c;
        if (col < NOUT) h2[(size_t)row * NOUT + col] = f2b(acc[t][r]);
      }
    }
  }
}

// ---------------- edge weights layer 2 ----------------
__global__ __launch_bounds__(256) void k_ew2(const int* __restrict__ eidx, const int* __restrict__ dpos,
                                             const float* __restrict__ al_s2, const float* __restrict__ al_d2,
                                             float* __restrict__ ew2){
  int p = blockIdx.x * 256 + threadIdx.x;
  if (p >= NETOT) return;
  ew2[p] = __expf(lrelu(al_s2[eidx[p]] + al_d2[dpos[p]]));
}

// ---------------- gather layer 2 + bias + log_softmax ----------------
__global__ __launch_bounds__(256) void k_gather2(const int* __restrict__ row_ptr, const int* __restrict__ eidx,
                                                 const float* __restrict__ ew2,
                                                 const bf16* __restrict__ h2, const bf16* __restrict__ b2v,
                                                 const int* __restrict__ flags, void* __restrict__ out){
  int lane = threadIdx.x & 63;
  int n = blockIdx.x * 4 + (threadIdx.x >> 6);
  int p0 = __builtin_amdgcn_readfirstlane(row_ptr[n]);
  int p1 = __builtin_amdgcn_readfirstlane(row_ptr[n + 1]);
  float den = 0.f, acc = 0.f;
  int p = p0;
  for (; p + 1 < p1; p += 2){
    int sA = __builtin_amdgcn_readfirstlane(eidx[p]);
    int sB = __builtin_amdgcn_readfirstlane(eidx[p + 1]);
    float wA = ew2[p], wB = ew2[p + 1];
    float hA = 0.f, hB = 0.f;
    if (lane < NOUT){
      hA = b2f(h2[(size_t)sA * NOUT + lane]);
      hB = b2f(h2[(size_t)sB * NOUT + lane]);
    }
    den += wA + wB;
    acc += wA * hA + wB * hB;
  }
  if (p < p1){
    int s = __builtin_amdgcn_readfirstlane(eidx[p]);
    float w = ew2[p];
    den += w;
    if (lane < NOUT) acc += w * b2f(h2[(size_t)s * NOUT + lane]);
  }
  float v = (lane < NOUT) ? (acc / (den + 1e-16f) + b2f(b2v[lane])) : -INFINITY;
  float M = wave_max(v);
  float ex = (lane < NOUT) ? __expf(v - M) : 0.f;
  float S = wave_sum(ex);
  if (lane < NOUT){
    float r = v - M - __logf(S);
    size_t idx = (size_t)n * NOUT + lane;
    if (flags[0]) ((float*)out)[idx] = r;
    else          ((bf16*)out)[idx]  = f2b(r);
  }
}

extern "C" void kernel_launch(void* const* d_in, const int* in_sizes, int n_in,
                              void* d_out, int out_size, void* d_ws, size_t ws_size,
                              hipStream_t stream) {
  const void* x   = d_in[0];
  const void* ei  = d_in[1];
  const void* W1  = d_in[2];
  const void* as1 = d_in[3];
  const void* ad1 = d_in[4];
  const void* b1  = d_in[5];
  const void* W2  = d_in[6];
  const void* as2 = d_in[7];
  const void* ad2 = d_in[8];
  const void* b2  = d_in[9];

  char* ws = (char*)d_ws;
  int*   flags   = (int*)  (ws + WS_FLAGS);
  float* ew1     = (float*)(ws + WS_EW1);
  bf16*  w1t     = (bf16*) (ws + WS_W1T);
  bf16*  as1n    = (bf16*) (ws + WS_AS1N);
  bf16*  ad1n    = (bf16*) (ws + WS_AD1N);
  bf16*  b1n     = (bf16*) (ws + WS_B1N);
  bf16*  w2t     = (bf16*) (ws + WS_W2T);
  bf16*  as2n    = (bf16*) (ws + WS_AS2N);
  bf16*  ad2n    = (bf16*) (ws + WS_AD2N);
  bf16*  b2n     = (bf16*) (ws + WS_B2N);
  int*   es      = (int*)  (ws + WS_ES);
  int*   ed      = (int*)  (ws + WS_ED);
  int*   counts  = (int*)  (ws + WS_COUNTS);
  int*   cursor  = (int*)  (ws + WS_CURSOR);
  int*   row_ptr = (int*)  (ws + WS_ROWPTR);
  int*   eidx    = (int*)  (ws + WS_EIDX);
  int*   dpos    = (int*)  (ws + WS_DPOS);
  unsigned char* h1q = (unsigned char*)(ws + WS_H1);
  float* al_s1   = (float*)(ws + WS_ALS1);
  float* al_d1   = (float*)(ws + WS_ALD1);
  bf16*  y1      = (bf16*) (ws + WS_Y1);
  bf16*  h2      = (bf16*) (ws + WS_H2);
  float* al_s2   = (float*)(ws + WS_ALS2);
  float* al_d2   = (float*)(ws + WS_ALD2);
  float* ew2     = (float*)(ws + WS_EW2);
  int*   bsum    = (int*)  (ws + WS_BSUM);
  int*   boff    = (int*)  (ws + WS_BOFF);

  hipMemsetAsync(counts, 0, (size_t)NN * 4, stream);
  hipMemsetAsync(cursor, 0, (size_t)NN * 4, stream);
  hipMemsetAsync(w2t,    0, (size_t)NPAD * CIN * 2, stream);

  k_detect <<<1, 64, 0, stream>>>((const unsigned short*)x, (const unsigned*)ei, flags);
  k_convert<<<1024, 256, 0, stream>>>(W1, as1, ad1, b1, W2, as2, ad2, b2, ei, ws);

  int eb = (NETOT + 255) / 256;
  k_scan_part <<<SCB, 256, 0, stream>>>(counts, bsum);
  k_scan_mid  <<<1, 256, 0, stream>>>(bsum, boff, row_ptr);
  k_scan_apply<<<SCB, 256, 0, stream>>>(counts, boff, row_ptr);
  k_scatter<<<eb, 256, 0, stream>>>(es, ed, row_ptr, cursor, eidx, dpos);

  k_gemm1  <<<(NN + G1R - 1) / G1R, 256, 0, stream>>>(x, flags, w1t, as1n, ad1n, h1q, al_s1, al_d1);
  k_ew1    <<<eb, 256, 0, stream>>>(eidx, dpos, al_s1, al_d1, (float4*)ew1);
  k_gather1<<<NN / 4, 256, 0, stream>>>(row_ptr, eidx, ew1, (const unsigned*)h1q, b1n, y1);
  k_gemm2  <<<(NN + 63) / 64, 256, 0, stream>>>(y1, w2t, as2n, ad2n, h2, al_s2, al_d2);
  k_ew2    <<<eb, 256, 0, stream>>>(eidx, dpos, al_s2, al_d2, ew2);
  k_gather2<<<NN / 4, 256, 0, stream>>>(row_ptr, eidx, ew2, h2, b2n, flags, d_out);
}

// Round 10
// 341.509 us; speedup vs baseline: 1.1509x; 1.0160x over previous
//
#include <hip/hip_runtime.h>
#include <hip/hip_bf16.h>

typedef __hip_bfloat16 bf16;
typedef short v8s __attribute__((ext_vector_type(8)));   // 8 bf16 (4 VGPRs), MFMA A/B frag
typedef float v4f __attribute__((ext_vector_type(4)));   // MFMA C/D frag

constexpr int NN    = 50000;   // nodes
constexpr int NE    = 800000;  // raw edges
constexpr int NETOT = 850000;  // + self loops
constexpr int CIN   = 256;
constexpr int HC    = 256;     // H*C
constexpr int NH    = 4;
constexpr int NOUT  = 40;
constexpr int NPAD  = 48;      // W2T padded cols (3 x 16)
constexpr int SCB   = 196;     // scan blocks (196*256 >= NN)

// ---------------- workspace layout ----------------
constexpr size_t al256(size_t x){ return (x + 255) & ~(size_t)255; }
constexpr size_t WS_FLAGS = 0;                                   // 2 ints
constexpr size_t WS_EW1   = 256;                                 // NETOT float4
constexpr size_t WS_W1T   = al256(WS_EW1   + (size_t)NETOT*16);  // [n][k] 256x256 bf16
constexpr size_t WS_AS1N  = al256(WS_W1T   + (size_t)CIN*HC*2);
constexpr size_t WS_AD1N  = al256(WS_AS1N  + HC*2);
constexpr size_t WS_B1N   = al256(WS_AD1N  + HC*2);
constexpr size_t WS_W2T   = al256(WS_B1N   + HC*2);              // [n][k] 48x256 bf16 (zero-padded)
constexpr size_t WS_AS2N  = al256(WS_W2T   + (size_t)NPAD*HC*2);
constexpr size_t WS_AD2N  = al256(WS_AS2N  + NOUT*2);
constexpr size_t WS_B2N   = al256(WS_AD2N  + NOUT*2);
constexpr size_t WS_COUNTS= al256(WS_B2N   + NOUT*2);
constexpr size_t WS_CURSOR= al256(WS_COUNTS+ (size_t)NN*4);
constexpr size_t WS_ROWPTR= al256(WS_CURSOR+ (size_t)NN*4);
constexpr size_t WS_EPAIR = al256(WS_ROWPTR+ (size_t)(NN+1)*4);  // NETOT int2 (s,d per CSR slot)
constexpr size_t WS_H1    = al256(WS_EPAIR + (size_t)NETOT*8);   // NN*HC fp8 (1B)
constexpr size_t WS_ALS1  = al256(WS_H1    + (size_t)NN*HC);
constexpr size_t WS_ALD1  = al256(WS_ALS1  + (size_t)NN*NH*4);
constexpr size_t WS_Y1    = al256(WS_ALD1  + (size_t)NN*NH*4);   // NN*HC bf16
constexpr size_t WS_H2    = al256(WS_Y1    + (size_t)NN*HC*2);   // NN*NOUT bf16
constexpr size_t WS_ALS2  = al256(WS_H2    + (size_t)NN*NOUT*2);
constexpr size_t WS_ALD2  = al256(WS_ALS2  + (size_t)NN*4);
constexpr size_t WS_EW2   = al256(WS_ALD2  + (size_t)NN*4);      // NETOT float
constexpr size_t WS_BSUM  = al256(WS_EW2   + (size_t)NETOT*4);   // 256 int
constexpr size_t WS_BOFF  = al256(WS_BSUM  + 1024);              // 256 int

// ---------------- convert virtual index space (weights + histogram) ---------
constexpr int CV_W1  = 0;
constexpr int CV_AS1 = CV_W1  + CIN*HC;
constexpr int CV_AD1 = CV_AS1 + HC;
constexpr int CV_B1  = CV_AD1 + HC;
constexpr int CV_W2  = CV_B1  + HC;
constexpr int CV_AS2 = CV_W2  + HC*NOUT;
constexpr int CV_AD2 = CV_AS2 + NOUT;
constexpr int CV_B2  = CV_AD2 + NOUT;
constexpr int CV_HIST= CV_B2  + NOUT;
constexpr int CV_END = CV_HIST + NE;

__device__ __forceinline__ float b2f(bf16 v) { return __bfloat162float(v); }
__device__ __forceinline__ bf16  f2b(float v){ return __float2bfloat16(v); }
__device__ __forceinline__ float bits2f(unsigned short u){ return __uint_as_float(((unsigned)u) << 16); }
__device__ __forceinline__ unsigned short f2bits(float v){
  bf16 t = __float2bfloat16(v);
  return *reinterpret_cast<unsigned short*>(&t);
}
__device__ __forceinline__ float lrelu(float x){ return x > 0.f ? x : 0.2f * x; }

__device__ __forceinline__ float wave_sum(float v){
  #pragma unroll
  for (int off = 32; off; off >>= 1) v += __shfl_xor(v, off, 64);
  return v;
}
__device__ __forceinline__ float wave_max(float v){
  #pragma unroll
  for (int off = 32; off; off >>= 1) v = fmaxf(v, __shfl_xor(v, off, 64));
  return v;
}

// ---------------- dtype detection ----------------
__global__ __launch_bounds__(64) void k_detect(const unsigned short* __restrict__ xu,
                                               const unsigned* __restrict__ eu,
                                               int* __restrict__ flags){
  int lane = threadIdx.x;
  int cnt = 0;
  for (int i = lane; i < 256; i += 64){
    int e = (xu[i] >> 7) & 0xFF;
    cnt += (e >= 0x60 && e <= 0x8F) ? 1 : 0;
  }
  #pragma unroll
  for (int off = 32; off; off >>= 1) cnt += __shfl_xor(cnt, off, 64);
  unsigned odd = eu[2 * lane + 1];
  #pragma unroll
  for (int off = 32; off; off >>= 1) odd |= __shfl_xor(odd, off, 64);
  if (lane == 0){
    flags[0] = (cnt < 218) ? 1 : 0;   // 1 = floats are f32
    flags[1] = (odd == 0)  ? 1 : 0;   // 1 = edges are int64
  }
}

__device__ __forceinline__ bf16 cvt_b(const void* src, int i, int f32m){
  if (f32m) return __float2bfloat16(((const float*)src)[i]);
  return ((const bf16*)src)[i];
}

// convert (weights only) + histogram over dst read straight from d_in
__global__ __launch_bounds__(256) void k_convert(
    const void* __restrict__ W1,
    const void* __restrict__ as1,const void* __restrict__ ad1,
    const void* __restrict__ b1, const void* __restrict__ W2,
    const void* __restrict__ as2,const void* __restrict__ ad2,
    const void* __restrict__ b2, const void* __restrict__ ei,
    char* __restrict__ ws){
  const int* flags = (const int*)(ws + WS_FLAGS);
  int f32m = flags[0], i64m = flags[1];
  bf16* w1t  = (bf16*)(ws + WS_W1T);
  bf16* as1n = (bf16*)(ws + WS_AS1N);
  bf16* ad1n = (bf16*)(ws + WS_AD1N);
  bf16* b1n  = (bf16*)(ws + WS_B1N);
  bf16* w2t  = (bf16*)(ws + WS_W2T);
  bf16* as2n = (bf16*)(ws + WS_AS2N);
  bf16* ad2n = (bf16*)(ws + WS_AD2N);
  bf16* b2n  = (bf16*)(ws + WS_B2N);
  int*  counts=(int*) (ws + WS_COUNTS);
  for (int g = blockIdx.x * 256 + threadIdx.x; g < CV_END; g += gridDim.x * 256){
    if      (g < CV_AS1){ int i = g-CV_W1; int k = i >> 8, n = i & 255;
      w1t[n*CIN + k] = cvt_b(W1, i, f32m); }                       // transpose
    else if (g < CV_AD1) as1n[g-CV_AS1] = cvt_b(as1,g-CV_AS1, f32m);
    else if (g < CV_B1 ) ad1n[g-CV_AD1] = cvt_b(ad1,g-CV_AD1, f32m);
    else if (g < CV_W2 ) b1n [g-CV_B1 ] = cvt_b(b1, g-CV_B1,  f32m);
    else if (g < CV_AS2){ int i = g-CV_W2; int k = i / NOUT, n = i - k*NOUT;
      w2t[n*CIN + k] = cvt_b(W2, i, f32m); }                       // transpose (rows 40..47 pre-zeroed)
    else if (g < CV_AD2) as2n[g-CV_AS2] = cvt_b(as2,g-CV_AS2, f32m);
    else if (g < CV_B2 ) ad2n[g-CV_AD2] = cvt_b(ad2,g-CV_AD2, f32m);
    else if (g < CV_HIST) b2n[g-CV_B2 ] = cvt_b(b2, g-CV_B2,  f32m);
    else { int i = g-CV_HIST;
      int d = i64m ? (int)((const long long*)ei)[(size_t)NE+i] : ((const int*)ei)[NE+i];
      atomicAdd(&counts[d], 1); }
  }
}

// ---------------- parallel CSR scan ----------------
__global__ __launch_bounds__(256) void k_scan_part(const int* __restrict__ counts, int* __restrict__ bsum){
  __shared__ int lds[256];
  int t = threadIdx.x;
  int idx = blockIdx.x * 256 + t;
  int v = (idx < NN) ? counts[idx] + 1 : 0;
  lds[t] = v;
  #pragma unroll
  for (int s = 128; s > 0; s >>= 1){
    __syncthreads();
    if (t < s) lds[t] += lds[t + s];
  }
  if (t == 0) bsum[blockIdx.x] = lds[0];
}

__global__ __launch_bounds__(256) void k_scan_mid(const int* __restrict__ bsum, int* __restrict__ boff,
                                                  int* __restrict__ row_ptr){
  __shared__ int lds[256];
  int t = threadIdx.x;
  int v = (t < SCB) ? bsum[t] : 0;
  lds[t] = v;
  for (int off = 1; off < 256; off <<= 1){
    __syncthreads();
    int u = (t >= off) ? lds[t - off] : 0;
    __syncthreads();
    lds[t] += u;
  }
  __syncthreads();
  if (t < SCB) boff[t] = lds[t] - v;   // exclusive
  if (t == 0) row_ptr[NN] = NETOT;
}

__global__ __launch_bounds__(256) void k_scan_apply(const int* __restrict__ counts, const int* __restrict__ boff,
                                                    int* __restrict__ row_ptr){
  __shared__ int lds[256];
  int t = threadIdx.x;
  int idx = blockIdx.x * 256 + t;
  int v = (idx < NN) ? counts[idx] + 1 : 0;
  lds[t] = v;
  for (int off = 1; off < 256; off <<= 1){
    __syncthreads();
    int u = (t >= off) ? lds[t - off] : 0;
    __syncthreads();
    lds[t] += u;
  }
  __syncthreads();
  if (idx < NN) row_ptr[idx] = boff[blockIdx.x] + lds[t] - v;
}

// scatter: single packed 8B store per edge (one dirtied line, not two)
__global__ __launch_bounds__(256) void k_scatter(const void* __restrict__ ei, const int* __restrict__ flags,
                                                 const int* __restrict__ row_ptr,
                                                 int* __restrict__ cursor, int2* __restrict__ epair){
  int i = blockIdx.x * 256 + threadIdx.x;
  if (i >= NETOT) return;
  int s, d;
  if (i < NE){
    if (flags[1]){ s = (int)((const long long*)ei)[i]; d = (int)((const long long*)ei)[(size_t)NE + i]; }
    else         { s = ((const int*)ei)[i];            d = ((const int*)ei)[NE + i]; }
  } else { s = i - NE; d = i - NE; }
  int pos = row_ptr[d] + atomicAdd(&cursor[d], 1);
  epair[pos] = make_int2(s, d);
}

// ---------------- GEMM1 (MFMA, LDS-staged) + fused al1 + fp8 h1 store ---------
constexpr int G1R = 64;                 // rows per block
constexpr int LP  = 72;                 // padded LDS row (elems)
__global__ __launch_bounds__(256) void k_gemm1(const void* __restrict__ xin,
                                               const int* __restrict__ flags,
                                               const bf16* __restrict__ w1t,
                                               const bf16* __restrict__ as1, const bf16* __restrict__ ad1,
                                               unsigned char* __restrict__ h1q,
                                               float* __restrict__ al_s1, float* __restrict__ al_d1){
  __shared__ short Ab[G1R * LP];
  __shared__ short Bb[256 * LP];
  int tid  = threadIdx.x;
  int w    = tid >> 6, lane = tid & 63, quad = lane >> 4, c = lane & 15;
  int row0 = blockIdx.x * G1R;
  int f32m = flags[0];

  v4f acc[4][4];
  #pragma unroll
  for (int mt = 0; mt < 4; ++mt)
    #pragma unroll
    for (int nt = 0; nt < 4; ++nt) acc[mt][nt] = (v4f){0.f,0.f,0.f,0.f};

  int arow = tid >> 2;
  int aseg = tid & 3;
  int grow = row0 + arow; if (grow >= NN) grow = NN - 1;

  for (int ph = 0; ph < 4; ++ph){
    if (ph) __syncthreads();
    {
      short va[16];
      if (f32m){
        const float* src = (const float*)xin + (size_t)grow * CIN + ph*64 + aseg*16;
        #pragma unroll
        for (int i = 0; i < 4; ++i){
          float4 f = *reinterpret_cast<const float4*>(src + i*4);
          va[i*4+0] = (short)f2bits(f.x); va[i*4+1] = (short)f2bits(f.y);
          va[i*4+2] = (short)f2bits(f.z); va[i*4+3] = (short)f2bits(f.w);
        }
      } else {
        const short* src = (const short*)xin + (size_t)grow * CIN + ph*64 + aseg*16;
        v8s u0 = *reinterpret_cast<const v8s*>(src);
        v8s u1 = *reinterpret_cast<const v8s*>(src + 8);
        #pragma unroll
        for (int i = 0; i < 8; ++i){ va[i] = u0[i]; va[8+i] = u1[i]; }
      }
      short* dst = &Ab[arow * LP + aseg * 16];
      *reinterpret_cast<v8s*>(dst)     = *reinterpret_cast<v8s*>(&va[0]);
      *reinterpret_cast<v8s*>(dst + 8) = *reinterpret_cast<v8s*>(&va[8]);
    }
    {
      const short* src = (const short*)w1t + (size_t)tid * CIN + ph*64;
      short* dst = &Bb[tid * LP];
      #pragma unroll
      for (int j = 0; j < 8; ++j)
        *reinterpret_cast<v8s*>(dst + j*8) = *reinterpret_cast<const v8s*>(src + j*8);
    }
    __syncthreads();
    #pragma unroll
    for (int s = 0; s < 2; ++s){
      int ch = s*4 + quad;
      v8s af[4], bfb[4];
      #pragma unroll
      for (int mt = 0; mt < 4; ++mt)
        af[mt] = *reinterpret_cast<const v8s*>(&Ab[(mt*16 + c) * LP + ch*8]);
      #pragma unroll
      for (int nt = 0; nt < 4; ++nt)
        bfb[nt] = *reinterpret_cast<const v8s*>(&Bb[(w*64 + nt*16 + c) * LP + ch*8]);
      #pragma unroll
      for (int mt = 0; mt < 4; ++mt)
        #pragma unroll
        for (int nt = 0; nt < 4; ++nt)
          acc[mt][nt] = __builtin_amdgcn_mfma_f32_16x16x32_bf16(af[mt], bfb[nt], acc[mt][nt], 0, 0, 0);
    }
  }

  float as1v[4], ad1v[4];
  #pragma unroll
  for (int nt = 0; nt < 4; ++nt){
    as1v[nt] = b2f(as1[w*64 + nt*16 + c]);
    ad1v[nt] = b2f(ad1[w*64 + nt*16 + c]);
  }
  #pragma unroll
  for (int mt = 0; mt < 4; ++mt){
    #pragma unroll
    for (int r = 0; r < 4; ++r){
      float ps = 0.f, pd = 0.f;
      #pragma unroll
      for (int nt = 0; nt < 4; ++nt){ ps += acc[mt][nt][r] * as1v[nt]; pd += acc[mt][nt][r] * ad1v[nt]; }
      #pragma unroll
      for (int off = 1; off < 16; off <<= 1){ ps += __shfl_xor(ps, off, 64); pd += __shfl_xor(pd, off, 64); }
      int row = row0 + mt*16 + quad*4 + r;
      if (c == 0 && row < NN){
        al_s1[row * NH + w] = ps;
        al_d1[row * NH + w] = pd;
      }
    }
  }
  #pragma unroll
  for (int mt = 0; mt < 4; ++mt){
    #pragma unroll
    for (int nt = 0; nt < 4; ++nt){
      #pragma unroll
      for (int r = 0; r < 4; r += 2){
        int row = row0 + mt*16 + quad*4 + r;
        if (row + 1 < NN){
          int pk = __builtin_amdgcn_cvt_pk_fp8_f32(acc[mt][nt][r], acc[mt][nt][r+1], 0, false);
          size_t col = w*64 + nt*16 + c;
          h1q[(size_t)row       * HC + col] = (unsigned char)(pk & 0xFF);
          h1q[(size_t)(row + 1) * HC + col] = (unsigned char)((pk >> 8) & 0xFF);
        } else if (row < NN){
          int pk = __builtin_amdgcn_cvt_pk_fp8_f32(acc[mt][nt][r], acc[mt][nt][r], 0, false);
          h1q[(size_t)row * HC + w*64 + nt*16 + c] = (unsigned char)(pk & 0xFF);
        }
      }
    }
  }
}

// ---------------- edge weights layer 1 ----------------
__global__ __launch_bounds__(256) void k_ew1(const int2* __restrict__ epair,
                                             const float* __restrict__ al_s1, const float* __restrict__ al_d1,
                                             float4* __restrict__ ew1){
  int p = blockIdx.x * 256 + threadIdx.x;
  if (p >= NETOT) return;
  int2 pr = epair[p];
  float4 as = reinterpret_cast<const float4*>(al_s1)[pr.x];
  float4 ad = reinterpret_cast<const float4*>(al_d1)[pr.y];
  float4 w;
  w.x = __expf(lrelu(as.x + ad.x));
  w.y = __expf(lrelu(as.y + ad.y));
  w.z = __expf(lrelu(as.z + ad.z));
  w.w = __expf(lrelu(as.w + ad.w));
  ew1[p] = w;
}

// ---------------- gather layer 1 ----------------
__global__ __launch_bounds__(256) void k_gather1(const int* __restrict__ row_ptr, const int2* __restrict__ epair,
                                                 const float* __restrict__ ew1,
                                                 const unsigned* __restrict__ h1v, const bf16* __restrict__ b1,
                                                 bf16* __restrict__ y1){
  int lane = threadIdx.x & 63;
  int n = blockIdx.x * 4 + (threadIdx.x >> 6);
  int h = lane >> 4;
  int p0 = __builtin_amdgcn_readfirstlane(row_ptr[n]);
  int p1 = __builtin_amdgcn_readfirstlane(row_ptr[n + 1]);
  float den = 0.f, a0 = 0.f, a1 = 0.f, a2 = 0.f, a3 = 0.f;
  int p = p0;
  for (; p + 1 < p1; p += 2){
    int sA = __builtin_amdgcn_readfirstlane(epair[p].x);
    int sB = __builtin_amdgcn_readfirstlane(epair[p + 1].x);
    float wA = ew1[(size_t)p * 4 + h];
    float wB = ew1[(size_t)(p + 1) * 4 + h];
    unsigned uA = h1v[(size_t)sA * 64 + lane];
    unsigned uB = h1v[(size_t)sB * 64 + lane];
    den += wA + wB;
    a0 += wA * __builtin_amdgcn_cvt_f32_fp8(uA, 0) + wB * __builtin_amdgcn_cvt_f32_fp8(uB, 0);
    a1 += wA * __builtin_amdgcn_cvt_f32_fp8(uA, 1) + wB * __builtin_amdgcn_cvt_f32_fp8(uB, 1);
    a2 += wA * __builtin_amdgcn_cvt_f32_fp8(uA, 2) + wB * __builtin_amdgcn_cvt_f32_fp8(uB, 2);
    a3 += wA * __builtin_amdgcn_cvt_f32_fp8(uA, 3) + wB * __builtin_amdgcn_cvt_f32_fp8(uB, 3);
  }
  if (p < p1){
    int s = __builtin_amdgcn_readfirstlane(epair[p].x);
    float w = ew1[(size_t)p * 4 + h];
    unsigned u = h1v[(size_t)s * 64 + lane];
    den += w;
    a0 += w * __builtin_amdgcn_cvt_f32_fp8(u, 0);
    a1 += w * __builtin_amdgcn_cvt_f32_fp8(u, 1);
    a2 += w * __builtin_amdgcn_cvt_f32_fp8(u, 2);
    a3 += w * __builtin_amdgcn_cvt_f32_fp8(u, 3);
  }
  float inv = 1.f / (den + 1e-16f);
  ushort4 bb = reinterpret_cast<const ushort4*>(b1)[lane];
  ushort4 o;
  o.x = f2bits(fmaxf(a0 * inv + bits2f(bb.x), 0.f));
  o.y = f2bits(fmaxf(a1 * inv + bits2f(bb.y), 0.f));
  o.z = f2bits(fmaxf(a2 * inv + bits2f(bb.z), 0.f));
  o.w = f2bits(fmaxf(a3 * inv + bits2f(bb.w), 0.f));
  reinterpret_cast<ushort4*>(y1)[(size_t)n * 64 + lane] = o;
}

// ---------------- GEMM2 (MFMA, W2T in LDS) + fused al_s2/al_d2 ----------------
constexpr int W2LP = 260;
__global__ __launch_bounds__(256) void k_gemm2(const bf16* __restrict__ y1, const bf16* __restrict__ w2t,
                                               const bf16* __restrict__ as2, const bf16* __restrict__ ad2,
                                               bf16* __restrict__ h2, float* __restrict__ al_s2,
                                               float* __restrict__ al_d2){
  __shared__ short Wb[NPAD * W2LP];
  int tid = threadIdx.x;
  int w = tid >> 6, lane = tid & 63, quad = lane >> 4, c = lane & 15;
  int m0 = blockIdx.x * 64 + w * 16;
  for (int idx = tid; idx < NPAD * 32; idx += 256){
    int n = idx >> 5, sg = idx & 31;
    *reinterpret_cast<v8s*>(&Wb[n * W2LP + sg * 8]) =
      *reinterpret_cast<const v8s*>((const short*)w2t + (size_t)n * CIN + sg * 8);
  }
  int arow = m0 + c; if (arow >= NN) arow = NN - 1;
  const short* ar = (const short*)y1 + (size_t)arow * HC + quad * 8;
  v8s a[8];
  #pragma unroll
  for (int i = 0; i < 8; ++i) a[i] = *reinterpret_cast<const v8s*>(ar + i * 32);
  __syncthreads();

  v4f acc[3];
  #pragma unroll
  for (int t = 0; t < 3; ++t) acc[t] = (v4f){0.f, 0.f, 0.f, 0.f};
  #pragma unroll
  for (int k = 0; k < 8; ++k){
    int ch = k*4 + quad;
    #pragma unroll
    for (int t = 0; t < 3; ++t){
      v8s b = *reinterpret_cast<const v8s*>(&Wb[(t*16 + c) * W2LP + ch * 8]);
      acc[t] = __builtin_amdgcn_mfma_f32_16x16x32_bf16(a[k], b, acc[t], 0, 0, 0);
    }
  }
  float as2f[3], ad2f[3];
  #pragma unroll
  for (int t = 0; t < 3; ++t){
    int col = t*16 + c;
    as2f[t] = (col < NOUT) ? b2f(as2[col]) : 0.f;
    ad2f[t] = (col < NOUT) ? b2f(ad2[col]) : 0.f;
  }
  #pragma unroll
  for (int r = 0; r < 4; ++r){
    int row = m0 + quad*4 + r;
    float ps = 0.f, pd = 0.f;
    #pragma unroll
    for (int t = 0; t < 3; ++t){ ps += acc[t][r] * as2f[t]; pd += acc[t][r] * ad2f[t]; }
    #pragma unroll
    for (int off = 1; off < 16; off <<= 1){ ps += __shfl_xor(ps, off, 64); pd += __shfl_xor(pd, off, 64); }
    if (row < NN){
      if (c == 0){ al_s2[row] = ps; al_d2[row] = pd; }
      #pragma unroll
      for (int t = 0; t < 3; ++t){
        int col = t*16 + c;
        if (col < NOUT) h2[(size_t)row * NOUT + col] = f2b(acc[t][r]);
      }
    }
  }
}

// ---------------- edge weights layer 2 ----------------
__global__ __launch_bounds__(256) void k_ew2(const int2* __restrict__ epair,
                                             const float* __restrict__ al_s2, const float* __restrict__ al_d2,
                                             float* __restrict__ ew2){
  int p = blockIdx.x * 256 + threadIdx.x;
  if (p >= NETOT) return;
  int2 pr = epair[p];
  ew2[p] = __expf(lrelu(al_s2[pr.x] + al_d2[pr.y]));
}

// ---------------- gather layer 2 + bias + log_softmax ----------------
__global__ __launch_bounds__(256) void k_gather2(const int* __restrict__ row_ptr, const int2* __restrict__ epair,
                                                 const float* __restrict__ ew2,
                                                 const bf16* __restrict__ h2, const bf16* __restrict__ b2v,
                                                 const int* __restrict__ flags, void* __restrict__ out){
  int lane = threadIdx.x & 63;
  int n = blockIdx.x * 4 + (threadIdx.x >> 6);
  int p0 = __builtin_amdgcn_readfirstlane(row_ptr[n]);
  int p1 = __builtin_amdgcn_readfirstlane(row_ptr[n + 1]);
  float den = 0.f, acc = 0.f;
  int p = p0;
  for (; p + 1 < p1; p += 2){
    int sA = __builtin_amdgcn_readfirstlane(epair[p].x);
    int sB = __builtin_amdgcn_readfirstlane(epair[p + 1].x);
    float wA = ew2[p], wB = ew2[p + 1];
    float hA = 0.f, hB = 0.f;
    if (lane < NOUT){
      hA = b2f(h2[(size_t)sA * NOUT + lane]);
      hB = b2f(h2[(size_t)sB * NOUT + lane]);
    }
    den += wA + wB;
    acc += wA * hA + wB * hB;
  }
  if (p < p1){
    int s = __builtin_amdgcn_readfirstlane(epair[p].x);
    float w = ew2[p];
    den += w;
    if (lane < NOUT) acc += w * b2f(h2[(size_t)s * NOUT + lane]);
  }
  float v = (lane < NOUT) ? (acc / (den + 1e-16f) + b2f(b2v[lane])) : -INFINITY;
  float M = wave_max(v);
  float ex = (lane < NOUT) ? __expf(v - M) : 0.f;
  float S = wave_sum(ex);
  if (lane < NOUT){
    float r = v - M - __logf(S);
    size_t idx = (size_t)n * NOUT + lane;
    if (flags[0]) ((float*)out)[idx] = r;
    else          ((bf16*)out)[idx]  = f2b(r);
  }
}

extern "C" void kernel_launch(void* const* d_in, const int* in_sizes, int n_in,
                              void* d_out, int out_size, void* d_ws, size_t ws_size,
                              hipStream_t stream) {
  const void* x   = d_in[0];
  const void* ei  = d_in[1];
  const void* W1  = d_in[2];
  const void* as1 = d_in[3];
  const void* ad1 = d_in[4];
  const void* b1  = d_in[5];
  const void* W2  = d_in[6];
  const void* as2 = d_in[7];
  const void* ad2 = d_in[8];
  const void* b2  = d_in[9];

  char* ws = (char*)d_ws;
  int*   flags   = (int*)  (ws + WS_FLAGS);
  float* ew1     = (float*)(ws + WS_EW1);
  bf16*  w1t     = (bf16*) (ws + WS_W1T);
  bf16*  as1n    = (bf16*) (ws + WS_AS1N);
  bf16*  ad1n    = (bf16*) (ws + WS_AD1N);
  bf16*  b1n     = (bf16*) (ws + WS_B1N);
  bf16*  w2t     = (bf16*) (ws + WS_W2T);
  bf16*  as2n    = (bf16*) (ws + WS_AS2N);
  bf16*  ad2n    = (bf16*) (ws + WS_AD2N);
  bf16*  b2n     = (bf16*) (ws + WS_B2N);
  int*   counts  = (int*)  (ws + WS_COUNTS);
  int*   cursor  = (int*)  (ws + WS_CURSOR);
  int*   row_ptr = (int*)  (ws + WS_ROWPTR);
  int2*  epair   = (int2*) (ws + WS_EPAIR);
  unsigned char* h1q = (unsigned char*)(ws + WS_H1);
  float* al_s1   = (float*)(ws + WS_ALS1);
  float* al_d1   = (float*)(ws + WS_ALD1);
  bf16*  y1      = (bf16*) (ws + WS_Y1);
  bf16*  h2      = (bf16*) (ws + WS_H2);
  float* al_s2   = (float*)(ws + WS_ALS2);
  float* al_d2   = (float*)(ws + WS_ALD2);
  float* ew2     = (float*)(ws + WS_EW2);
  int*   bsum    = (int*)  (ws + WS_BSUM);
  int*   boff    = (int*)  (ws + WS_BOFF);

  hipMemsetAsync(counts, 0, (size_t)NN * 4, stream);
  hipMemsetAsync(cursor, 0, (size_t)NN * 4, stream);
  hipMemsetAsync(w2t,    0, (size_t)NPAD * CIN * 2, stream);

  k_detect <<<1, 64, 0, stream>>>((const unsigned short*)x, (const unsigned*)ei, flags);
  k_convert<<<1024, 256, 0, stream>>>(W1, as1, ad1, b1, W2, as2, ad2, b2, ei, ws);

  int eb = (NETOT + 255) / 256;
  k_scan_part <<<SCB, 256, 0, stream>>>(counts, bsum);
  k_scan_mid  <<<1, 256, 0, stream>>>(bsum, boff, row_ptr);
  k_scan_apply<<<SCB, 256, 0, stream>>>(counts, boff, row_ptr);
  k_scatter<<<eb, 256, 0, stream>>>(ei, flags, row_ptr, cursor, epair);

  k_gemm1  <<<(NN + G1R - 1) / G1R, 256, 0, stream>>>(x, flags, w1t, as1n, ad1n, h1q, al_s1, al_d1);
  k_ew1    <<<eb, 256, 0, stream>>>(epair, al_s1, al_d1, (float4*)ew1);
  k_gather1<<<NN / 4, 256, 0, stream>>>(row_ptr, epair, ew1, (const unsigned*)h1q, b1n, y1);
  k_gemm2  <<<(NN + 63) / 64, 256, 0, stream>>>(y1, w2t, as2n, ad2n, h2, al_s2, al_d2);
  k_ew2    <<<eb, 256, 0, stream>>>(epair, al_s2, al_d2, ew2);
  k_gather2<<<NN / 4, 256, 0, stream>>>(row_ptr, epair, ew2, h2, b2n, flags, d_out);
}